// Round 2
// baseline (192.908 us; speedup 1.0000x reference)
//
#include <hip/hip_runtime.h>
#include <hip/hip_bf16.h>

// Problem constants (M is a static constant in the reference; N,E derived from in_sizes)
#define D 128
#define MSEG 10000
#define CB 128       // coarse buckets per direction (128 -> build_csr fills all 256 CUs)
#define CAP 8192     // pairs capacity per bucket region (expected ~3906, 2.1x headroom)

typedef __attribute__((ext_vector_type(8))) __bf16 bf16x8;
typedef __attribute__((ext_vector_type(4))) float f32x4;

// ALGEBRAIC FOLD (R2): seg_mean is linear, so
//   n_agg = seg_mean(e_feat @ We) = seg_mean(e_feat) @ We
//   out   = relu([xp | seg_mean(e_feat)] @ [Wu_top ; We@Wu_bot] + b)
// We precompute Wc = We @ Wu_bot once (one MFMA tile block, hidden inside the
// gemmv_scatter dispatch) -> middle GEMM dispatch and e_proj tensor deleted.
// The N-direction aggregation is fused into the final GEMM (per-tile LDS gather)
// -> n_agg tensor and its dispatch deleted. 7 dispatches -> 5.

__device__ __forceinline__ int cbkt(int c, int M) { return (c * CB) / M; }
__device__ __forceinline__ int rbkt(int r, int N) { return (int)(((long long)r * CB) / N); }

#if __has_builtin(__builtin_amdgcn_global_load_lds)
typedef __attribute__((address_space(1))) const unsigned int gu32;
typedef __attribute__((address_space(3))) unsigned int lu32;
__device__ __forceinline__ void dma16(const void* g, void* l) {
    __builtin_amdgcn_global_load_lds((gu32*)g, (lu32*)l, 16, 0, 0);
}
#else
__device__ __forceinline__ void dma16(const void* g, void* l) {
    *(bf16x8*)l = *(const bf16x8*)g;
}
#endif

// ---------------- FUSED: gemm_v [0,NGB) | Wc tile (NGB) | counting scatter (NGB, NGB+SB] ----
// gemm blocks self-convert Wv (f32, L2-resident) into LDS planes; block NGB computes
// Wc = We @ Wu_bot via one MFMA tile and stores it plane-format to wp[16..31];
// first scatter block converts Wu_top into wp planes 0..15.
__global__ __launch_bounds__(256) void gemmv_scatter(
        const float* __restrict__ A0v, const float* __restrict__ Wv,
        const float* __restrict__ We, const float* __restrict__ Wu,
        __bf16* __restrict__ wp, __bf16* __restrict__ xp, int rows, int NGB,
        const int* __restrict__ row, const int* __restrict__ col, int n, int* __restrict__ gcursor,
        int2* __restrict__ cbins, int2* __restrict__ rbins, int M, int N) {
    __shared__ __bf16 Ws[16 * 128 * 8];   // 32KB
    __shared__ __bf16 As[2][4 * 128 * 8]; // 16KB
    __shared__ int lcur[2 * CB];          // 1KB
    int tid = threadIdx.x;

    if ((int)blockIdx.x > NGB) {
        // ======== scatter branch: 2048 pairs/block, one reservation per bucket per block
        if ((int)blockIdx.x == NGB + 1) {
            // convert Wu_top (rows 0..127) into wp planes 0..15.
            // plane layout: element (p,c,j) at ((p*128)+c)*8+j == W[p*8+j][c].
            #pragma unroll
            for (int it = 0; it < 8; ++it) {
                int idx = it * 256 + tid;        // 0..2047
                int pg = idx >> 7, c = idx & 127;
                union { bf16x8 v; __bf16 e[8]; } u;
                #pragma unroll
                for (int j = 0; j < 8; ++j) u.e[j] = (__bf16)Wu[(pg * 8 + j) * 128 + c];
                *(bf16x8*)&wp[(size_t)idx * 8] = u.v;
            }
        }
        lcur[tid] = 0;                    // 256 threads == 2*CB counters
        __syncthreads();
        int base = (blockIdx.x - NGB - 1) * 2048;
        int cc[8], rr[8], bc[8], br[8];
        #pragma unroll
        for (int u = 0; u < 8; ++u) {
            int i = base + u * 256 + tid;
            if (i < n) {
                int c = col[i], r = row[i];
                cc[u] = c; rr[u] = r;
                bc[u] = cbkt(c, M);
                br[u] = CB + rbkt(r, N);
                atomicAdd(&lcur[bc[u]], 1);
                atomicAdd(&lcur[br[u]], 1);
            } else bc[u] = -1;
        }
        __syncthreads();
        {
            int cnt = lcur[tid];
            int gb = (tid & (CB - 1)) * CAP + (cnt ? atomicAdd(&gcursor[tid], cnt) : 0);
            lcur[tid] = gb;               // absolute base within this dir's bins
        }
        __syncthreads();
        #pragma unroll
        for (int u = 0; u < 8; ++u) {
            if (bc[u] >= 0) {
                int pc = atomicAdd(&lcur[bc[u]], 1);
                if (pc < (bc[u] + 1) * CAP) cbins[pc] = make_int2(cc[u], rr[u]);
                int pr = atomicAdd(&lcur[br[u]], 1);
                int rb = br[u] - CB;
                if (pr < (rb + 1) * CAP) rbins[pr] = make_int2(rr[u], cc[u]);
            }
        }
        return;
    }

    // ======== gemm branch: xp tile = bf16(A@Wv)  |  Wc tile = We @ Wu_bot (block NGB)
    bool wc = ((int)blockIdx.x == NGB);
    const float* Asrc = wc ? We : A0v;
    const float* Wsrc = wc ? Wu + 128 * 128 : Wv;
    int rowsE = wc ? 128 : rows;
    int w = tid >> 6, lane = tid & 63;
    int quad = lane >> 4, l15 = lane & 15;
    int r0 = wc ? 0 : blockIdx.x * 128;
    int mh = (w >> 1) * 64, nh = (w & 1) * 64;

    // self-convert weight f32 -> bf16 planes in LDS
    #pragma unroll
    for (int it = 0; it < 8; ++it) {
        int idx = it * 256 + tid;         // 0..2047
        int pg = idx >> 7, c = idx & 127;
        union { bf16x8 v; __bf16 e[8]; } u;
        #pragma unroll
        for (int j = 0; j < 8; ++j) u.e[j] = (__bf16)Wsrc[(pg * 8 + j) * 128 + c];
        *(bf16x8*)&Ws[(size_t)idx * 8] = u.v;
    }
    f32x4 acc[4][4];
    {
        f32x4 z = {0.f, 0.f, 0.f, 0.f};
        #pragma unroll
        for (int i = 0; i < 4; ++i)
            #pragma unroll
            for (int j = 0; j < 4; ++j) acc[i][j] = z;
    }
    auto stageA = [&](int t, int b) {
        int k0 = t * 32;
        #pragma unroll
        for (int h = 0; h < 2; ++h) {
            int i = h * 256 + tid;
            int q = i >> 7, r = i & 127;
            int rr2 = min(r0 + r, rowsE - 1);
            const float* Ap = Asrc + (size_t)rr2 * D + k0 + q * 8;
            float4 f0 = *(const float4*)Ap;
            float4 f1 = *(const float4*)(Ap + 4);
            union { bf16x8 v; __bf16 e[8]; } u;
            u.e[0] = (__bf16)f0.x; u.e[1] = (__bf16)f0.y; u.e[2] = (__bf16)f0.z; u.e[3] = (__bf16)f0.w;
            u.e[4] = (__bf16)f1.x; u.e[5] = (__bf16)f1.y; u.e[6] = (__bf16)f1.z; u.e[7] = (__bf16)f1.w;
            *(bf16x8*)&As[b][i * 8] = u.v;
        }
    };
    stageA(0, 0);
    for (int t = 0; t < 4; ++t) {
        __syncthreads();
        if (t + 1 < 4) stageA(t + 1, (t + 1) & 1);
        int b = t & 1;
        bf16x8 af[4], bfr[4];
        #pragma unroll
        for (int mi = 0; mi < 4; ++mi)
            af[mi] = *(const bf16x8*)&As[b][(quad * 128 + mh + mi * 16 + l15) * 8];
        #pragma unroll
        for (int ni = 0; ni < 4; ++ni)
            bfr[ni] = *(const bf16x8*)&Ws[((t * 4 + quad) * 128 + nh + ni * 16 + l15) * 8];
        #pragma unroll
        for (int mi = 0; mi < 4; ++mi)
            #pragma unroll
            for (int ni = 0; ni < 4; ++ni)
                acc[mi][ni] = __builtin_amdgcn_mfma_f32_16x16x32_bf16(af[mi], bfr[ni], acc[mi][ni], 0, 0, 0);
    }
    #pragma unroll
    for (int ni = 0; ni < 4; ++ni) {
        int colc = nh + ni * 16 + l15;
        #pragma unroll
        for (int mi = 0; mi < 4; ++mi) {
            #pragma unroll
            for (int v = 0; v < 4; ++v) {
                int r = r0 + mh + mi * 16 + quad * 4 + v;
                if (wc) {
                    // Wc[r][c] -> final-W k-index 128+r -> plane 16+(r>>3), elem r&7
                    int rl = mh + mi * 16 + quad * 4 + v;
                    wp[(size_t)(((16 + (rl >> 3)) * 128 + colc) * 8) + (rl & 7)] = (__bf16)acc[mi][ni][v];
                } else if (r < rows) {
                    xp[(size_t)r * D + colc] = (__bf16)acc[mi][ni][v];
                }
            }
        }
    }
}

// ---------------- build CSR: one block per bucket (256 blocks = full machine) --------------
__global__ __launch_bounds__(512) void build_csr(const int2* __restrict__ cbins, const int2* __restrict__ rbins,
                                                 const int* __restrict__ gcursor,
                                                 int* __restrict__ coff, int* __restrict__ roff,
                                                 int* __restrict__ clist, int* __restrict__ rlist,
                                                 int M, int N, int E_) {
    __shared__ int hist[400];
    __shared__ int cur[400];
    __shared__ int slist[CAP];            // 32KB ordered bucket region
    __shared__ int wsum[8];
    __shared__ int sbase, scnt;
    int b = blockIdx.x, tid = threadIdx.x;
    int dir = b >> 7, bb = b & (CB - 1);
    int tot = dir ? N : M;
    int lo = (bb * tot + CB - 1) / CB;    // ceil(bb*tot/CB): first key in bucket
    int hi = ((bb + 1) * tot + CB - 1) / CB;
    int nb = hi - lo;                     // <= 391
    if (tid < 64) {                       // wave 0: per-dir prefix over 128 bucket counts
        int c0 = min(gcursor[dir * CB + 2 * tid], CAP);
        int c1 = min(gcursor[dir * CB + 2 * tid + 1], CAP);
        int ts = c0 + c1, incl = ts;
        #pragma unroll
        for (int o = 1; o < 64; o <<= 1) { int t = __shfl_up(incl, o, 64); if (tid >= o) incl += t; }
        if (tid == (bb >> 1)) { sbase = incl - ts + ((bb & 1) ? c0 : 0); scnt = (bb & 1) ? c1 : c0; }
    }
    for (int i = tid; i < nb; i += 512) hist[i] = 0;
    __syncthreads();
    int bcnt = scnt;
    int bstart = sbase;                   // CSR offset of this bucket
    const int2* bins = (dir ? rbins : cbins) + (size_t)bb * CAP;
    int* offp = dir ? roff : coff;
    int* list = dir ? rlist : clist;
    // load pass: pairs -> registers, histogram in LDS (bcnt <= CAP = 16*512)
    int2 pr[16];
    #pragma unroll
    for (int u = 0; u < 16; ++u) {
        int i = u * 512 + tid;
        if (i < bcnt) { pr[u] = bins[i]; atomicAdd(&hist[pr[u].x - lo], 1); }
        else pr[u].x = -1;
    }
    __syncthreads();
    // block exclusive scan over hist[0..nb)
    int lane = tid & 63, wv = tid >> 6;
    int a = (tid < nb) ? hist[tid] : 0;
    int incl = a;
    #pragma unroll
    for (int o = 1; o < 64; o <<= 1) { int t = __shfl_up(incl, o, 64); if (lane >= o) incl += t; }
    if (lane == 63) wsum[wv] = incl;
    __syncthreads();
    int wb = 0;
    for (int j = 0; j < wv; ++j) wb += wsum[j];
    int ex = bstart + wb + incl - a;
    if (tid < nb) { offp[lo + tid] = ex; cur[tid] = ex; }
    __syncthreads();
    // place pass: registers -> ordered LDS region
    #pragma unroll
    for (int u = 0; u < 16; ++u) {
        if (pr[u].x >= 0) {
            int p = atomicAdd(&cur[pr[u].x - lo], 1);
            slist[p - bstart] = pr[u].y;
        }
    }
    __syncthreads();
    // coalesced flush
    for (int i = tid; i < bcnt; i += 512) list[bstart + i] = slist[i];
    if (b == 0 && tid == 0) { coff[M] = E_; roff[N] = E_; }
}

// ---------------- segment mean via CSR: one wave = 4 entry slots x 16 lanes ----------------
__global__ __launch_bounds__(256) void agg_mean(const __bf16* __restrict__ src, const int* __restrict__ off,
                                                const int* __restrict__ list, __bf16* __restrict__ dst,
                                                int nseg) {
    int seg = blockIdx.x * 4 + (threadIdx.x >> 6);
    if (seg >= nseg) return;
    int lane = threadIdx.x & 63;
    int slot = lane >> 4, cg = lane & 15;
    int s = off[seg], e = off[seg + 1];
    int cnt = e - s;
    float acc[8];
    #pragma unroll
    for (int j = 0; j < 8; ++j) acc[j] = 0.f;

    int i = s;
    for (; i + 8 <= e; i += 8) {
        int r0 = list[i + slot];
        int r1 = list[i + 4 + slot];
        bf16x8 v0 = *(const bf16x8*)&src[(size_t)r0 * D + cg * 8];
        bf16x8 v1 = *(const bf16x8*)&src[(size_t)r1 * D + cg * 8];
        #pragma unroll
        for (int j = 0; j < 8; ++j) acc[j] += (float)v0[j] + (float)v1[j];
    }
    for (; i < e; i += 4) {
        int ii = i + slot;
        if (ii < e) {
            int r = list[ii];
            bf16x8 v = *(const bf16x8*)&src[(size_t)r * D + cg * 8];
            #pragma unroll
            for (int j = 0; j < 8; ++j) acc[j] += (float)v[j];
        }
    }
    #pragma unroll
    for (int j = 0; j < 8; ++j) {
        acc[j] += __shfl_xor(acc[j], 16, 64);
        acc[j] += __shfl_xor(acc[j], 32, 64);
    }
    if (slot == 0) {
        float inv = 1.f / (float)max(cnt, 1);
        union { bf16x8 v; __bf16 e[8]; } u;
        #pragma unroll
        for (int j = 0; j < 8; ++j) u.e[j] = (__bf16)(acc[j] * inv);
        *(bf16x8*)&dst[(size_t)seg * D + cg * 8] = u.v;
    }
}

// ---------------- FUSED final: per-tile gather-mean(e_feat) -> Agg, then -------------------
//   out = relu([xp | Agg] @ [Wu_top ; Wc] + b).   LDS 80KB -> 2 blocks/CU.
// Agg is XOR-swizzled (k8group ^ ((row&7)<<3)) so MFMA A-frag ds_read_b128 is
// conflict-free (16 lanes read 16 rows at same k-range).
__global__ __launch_bounds__(256) void gemm_final(
        const __bf16* __restrict__ xp, const __bf16* __restrict__ ef,
        const int* __restrict__ roff, const int* __restrict__ rlist,
        const __bf16* __restrict__ Wp, const float* __restrict__ bias,
        float* __restrict__ out, int rows) {
    __shared__ __bf16 Ws[16 * 128 * 8];   // 32KB (two-phase: planes 0..15 then 16..31)
    __shared__ __bf16 As[2][4 * 128 * 8]; // 16KB
    __shared__ __bf16 Agg[128 * 128];     // 32KB swizzled agg tile
    int tid = threadIdx.x;
    int w = tid >> 6, lane = tid & 63;
    int quad = lane >> 4, l15 = lane & 15;
    int r0 = blockIdx.x * 128;
    int mh = (w >> 1) * 64, nh = (w & 1) * 64;

    // DMA weight chunk 0 (planes 0..15 = Wu_top)
    #pragma unroll
    for (int it = 0; it < 8; ++it) {
        int idx = it * 256 + tid;
        dma16(Wp + (size_t)idx * 8, &Ws[(size_t)idx * 8]);
    }

    // ---- gather-mean phase: each wave does 32 segments, 4 entry-slots x 16 col-lanes
    for (int rd = 0; rd < 32; ++rd) {
        int rloc = w * 32 + rd;
        int seg = r0 + rloc;
        float acc8[8];
        #pragma unroll
        for (int j = 0; j < 8; ++j) acc8[j] = 0.f;
        int cnt = 0;
        if (seg < rows) {
            int s = roff[seg], e = roff[seg + 1];
            cnt = e - s;
            int i = s;
            for (; i + 8 <= e; i += 8) {
                int g0 = rlist[i + quad];
                int g1 = rlist[i + 4 + quad];
                bf16x8 v0 = *(const bf16x8*)&ef[(size_t)g0 * D + l15 * 8];
                bf16x8 v1 = *(const bf16x8*)&ef[(size_t)g1 * D + l15 * 8];
                #pragma unroll
                for (int j = 0; j < 8; ++j) acc8[j] += (float)v0[j] + (float)v1[j];
            }
            for (; i < e; i += 4) {
                int ii = i + quad;
                if (ii < e) {
                    int g = rlist[ii];
                    bf16x8 v = *(const bf16x8*)&ef[(size_t)g * D + l15 * 8];
                    #pragma unroll
                    for (int j = 0; j < 8; ++j) acc8[j] += (float)v[j];
                }
            }
        }
        #pragma unroll
        for (int j = 0; j < 8; ++j) {
            acc8[j] += __shfl_xor(acc8[j], 16, 64);
            acc8[j] += __shfl_xor(acc8[j], 32, 64);
        }
        if (quad == 0) {
            float inv = 1.f / (float)max(cnt, 1);
            union { bf16x8 v; __bf16 e[8]; } u;
            #pragma unroll
            for (int j = 0; j < 8; ++j) u.e[j] = (__bf16)(acc8[j] * inv);
            int kx = (l15 * 8) ^ ((rloc & 7) << 3);
            *(bf16x8*)&Agg[rloc * 128 + kx] = u.v;
        }
    }

    f32x4 acc[4][4];
    {
        f32x4 z = {0.f, 0.f, 0.f, 0.f};
        #pragma unroll
        for (int i = 0; i < 4; ++i)
            #pragma unroll
            for (int j = 0; j < 4; ++j) acc[i][j] = z;
    }
    auto stageA = [&](int t, int b) {
        int k0 = t * 32;
        #pragma unroll
        for (int h = 0; h < 2; ++h) {
            int i = h * 256 + tid;
            int q = i >> 7, r = i & 127;
            int rr = min(r0 + r, rows - 1);
            dma16(xp + (size_t)rr * D + k0 + q * 8, &As[b][i * 8]);
        }
    };

    // ---- K chunks 0..3: A = xp tile (double-buffered DMA), W = Wu_top
    stageA(0, 0);
    for (int t = 0; t < 4; ++t) {
        __syncthreads();                  // drains DMA (As chunk t, + Ws chunk0 on t=0)
        if (t + 1 < 4) stageA(t + 1, (t + 1) & 1);
        int b = t & 1;
        bf16x8 af[4], bfr[4];
        #pragma unroll
        for (int mi = 0; mi < 4; ++mi)
            af[mi] = *(const bf16x8*)&As[b][(quad * 128 + mh + mi * 16 + l15) * 8];
        #pragma unroll
        for (int ni = 0; ni < 4; ++ni)
            bfr[ni] = *(const bf16x8*)&Ws[((t * 4 + quad) * 128 + nh + ni * 16 + l15) * 8];
        #pragma unroll
        for (int mi = 0; mi < 4; ++mi)
            #pragma unroll
            for (int ni = 0; ni < 4; ++ni)
                acc[mi][ni] = __builtin_amdgcn_mfma_f32_16x16x32_bf16(af[mi], bfr[ni], acc[mi][ni], 0, 0, 0);
    }
    // ---- swap weights: planes 16..31 = Wc
    __syncthreads();                      // all waves done reading Ws chunk0
    #pragma unroll
    for (int it = 0; it < 8; ++it) {
        int idx = it * 256 + tid;
        dma16(Wp + (size_t)(2048 + idx) * 8, &Ws[(size_t)idx * 8]);
    }
    __syncthreads();                      // drains Ws chunk1
    // ---- K chunks 4..7: A = Agg (in LDS already), W = Wc
    for (int t = 4; t < 8; ++t) {
        bf16x8 af[4], bfr[4];
        int kb = (t - 4) * 32 + quad * 8;
        #pragma unroll
        for (int mi = 0; mi < 4; ++mi) {
            int row = mh + mi * 16 + l15;
            af[mi] = *(const bf16x8*)&Agg[row * 128 + (kb ^ ((row & 7) << 3))];
        }
        #pragma unroll
        for (int ni = 0; ni < 4; ++ni)
            bfr[ni] = *(const bf16x8*)&Ws[(((t - 4) * 4 + quad) * 128 + nh + ni * 16 + l15) * 8];
        #pragma unroll
        for (int mi = 0; mi < 4; ++mi)
            #pragma unroll
            for (int ni = 0; ni < 4; ++ni)
                acc[mi][ni] = __builtin_amdgcn_mfma_f32_16x16x32_bf16(af[mi], bfr[ni], acc[mi][ni], 0, 0, 0);
    }
    // ---- epilogue: bias + relu, f32 out
    #pragma unroll
    for (int ni = 0; ni < 4; ++ni) {
        int colc = nh + ni * 16 + l15;
        float bv = bias[colc];
        #pragma unroll
        for (int mi = 0; mi < 4; ++mi) {
            #pragma unroll
            for (int v = 0; v < 4; ++v) {
                int r = r0 + mh + mi * 16 + quad * 4 + v;
                if (r < rows) out[(size_t)r * D + colc] = fmaxf(acc[mi][ni][v] + bv, 0.f);
            }
        }
    }
}

extern "C" void kernel_launch(void* const* d_in, const int* in_sizes, int n_in,
                              void* d_out, int out_size, void* d_ws, size_t ws_size,
                              hipStream_t stream) {
    const float* x  = (const float*)d_in[0];
    const int*   ei = (const int*)d_in[1];
    const float* Wv = (const float*)d_in[2];
    const float* We = (const float*)d_in[3];
    const float* Wu = (const float*)d_in[4];
    const float* bu = (const float*)d_in[5];
    float* out = (float*)d_out;

    const int N = in_sizes[0] / D;       // 50000
    const int E = in_sizes[1] / 2;       // 500000
    const int M = MSEG;                  // 10000 (static in reference)
    const int* row = ei;
    const int* col = ei + E;

    // workspace carve-out (256B aligned)
    char* p = (char*)d_ws;
    auto alloc = [&](size_t bytes) { char* q = p; p += (bytes + 255) & ~(size_t)255; return q; };
    __bf16* xp     = (__bf16*)alloc((size_t)N * D * 2);   // 12.8MB
    __bf16* e_feat = (__bf16*)alloc((size_t)M * D * 2);   // 2.56MB
    __bf16* wp     = (__bf16*)alloc((size_t)32 * 128 * 8 * 2);   // 64KB [Wu_top|Wc] planes
    int* coff  = (int*)alloc((size_t)(M + 1) * 4);
    int* roff  = (int*)alloc((size_t)(N + 1) * 4);
    int* clist = (int*)alloc((size_t)E * 4);
    int* rlist = (int*)alloc((size_t)E * 4);
    int2* cbins = (int2*)alloc((size_t)CB * CAP * 8);     // 8MB
    int2* rbins = (int2*)alloc((size_t)CB * CAP * 8);     // 8MB
    int* gcursor = (int*)alloc(2 * CB * 4);               // 1KB counts (zeroed per launch)

    const int NGB = (N + 127) / 128;     // gemm_v blocks
    const int SB  = (E + 2047) / 2048;   // scatter blocks

    hipMemsetAsync(gcursor, 0, 2 * CB * sizeof(int), stream);
    gemmv_scatter<<<NGB + 1 + SB, 256, 0, stream>>>(x, Wv, We, Wu, wp, xp, N, NGB,
                                                    row, col, E, gcursor, cbins, rbins, M, N);
    build_csr<<<2 * CB, 512, 0, stream>>>(cbins, rbins, gcursor, coff, roff, clist, rlist, M, N, E);
    agg_mean<<<(M + 3) / 4, 256, 0, stream>>>(xp, coff, clist, e_feat, M);
    gemm_final<<<(N + 127) / 128, 256, 0, stream>>>(xp, e_feat, roff, rlist, wp, bu, out, N);
}

// Round 3
// 160.627 us; speedup vs baseline: 1.2010x; 1.2010x over previous
//
#include <hip/hip_runtime.h>
#include <hip/hip_bf16.h>

// Problem constants (M is a static constant in the reference; N,E derived from in_sizes)
#define D 128
#define MSEG 10000
#define CB 256       // coarse buckets per direction (512 blocks -> full machine in build_csr)
#define CAP 4096     // pairs capacity per bucket region (expected ~1953, 2.1x headroom)

typedef __attribute__((ext_vector_type(8))) __bf16 bf16x8;
typedef __attribute__((ext_vector_type(4))) float f32x4;

// ALGEBRAIC FOLD (R2, verified): seg_mean is linear, so
//   out = relu([x@Wv | seg_mean_row(seg_mean_col(x@Wv))] @ [Wu_top ; We@Wu_bot] + b)
// Wc = We@Wu_bot precomputed inside the gemmv_scatter dispatch -> middle GEMM deleted.
// R3: aggM fused INTO build_csr dir-0 blocks (pair lists already ordered in LDS) ->
// aggM dispatch + coff/clist round-trip deleted. aggN stays standalone (R2 lesson:
// per-tile serial gather collapses TLP; standalone has 50000 waves).

__device__ __forceinline__ int cbkt(int c, int M) { return (c * CB) / M; }
__device__ __forceinline__ int rbkt(int r, int N) { return (int)(((long long)r * CB) / N); }

#if __has_builtin(__builtin_amdgcn_global_load_lds)
typedef __attribute__((address_space(1))) const unsigned int gu32;
typedef __attribute__((address_space(3))) unsigned int lu32;
__device__ __forceinline__ void dma16(const void* g, void* l) {
    __builtin_amdgcn_global_load_lds((gu32*)g, (lu32*)l, 16, 0, 0);
}
#else
__device__ __forceinline__ void dma16(const void* g, void* l) {
    *(bf16x8*)l = *(const bf16x8*)g;
}
#endif

// ---------------- FUSED: gemm_v [0,NGB) | Wc tile (NGB) | counting scatter (NGB, NGB+SB] ----
__global__ __launch_bounds__(256) void gemmv_scatter(
        const float* __restrict__ A0v, const float* __restrict__ Wv,
        const float* __restrict__ We, const float* __restrict__ Wu,
        __bf16* __restrict__ wp, __bf16* __restrict__ xp, int rows, int NGB,
        const int* __restrict__ row, const int* __restrict__ col, int n, int* __restrict__ gcursor,
        int2* __restrict__ cbins, int2* __restrict__ rbins, int M, int N) {
    __shared__ __bf16 Ws[16 * 128 * 8];   // 32KB
    __shared__ __bf16 As[2][4 * 128 * 8]; // 16KB
    __shared__ int lcur[2 * CB];          // 2KB
    int tid = threadIdx.x;

    if ((int)blockIdx.x > NGB) {
        // ======== scatter branch: 2048 pairs/block, one reservation per bucket per block
        if ((int)blockIdx.x == NGB + 1) {
            // convert Wu_top (rows 0..127) into wp planes 0..15.
            // plane layout: element (p,c,j) at ((p*128)+c)*8+j == W[p*8+j][c].
            #pragma unroll
            for (int it = 0; it < 8; ++it) {
                int idx = it * 256 + tid;        // 0..2047
                int pg = idx >> 7, c = idx & 127;
                union { bf16x8 v; __bf16 e[8]; } u;
                #pragma unroll
                for (int j = 0; j < 8; ++j) u.e[j] = (__bf16)Wu[(pg * 8 + j) * 128 + c];
                *(bf16x8*)&wp[(size_t)idx * 8] = u.v;
            }
        }
        lcur[tid] = 0; lcur[tid + 256] = 0;
        __syncthreads();
        int base = (blockIdx.x - NGB - 1) * 2048;
        int cc[8], rr[8], bc[8], br[8];
        #pragma unroll
        for (int u = 0; u < 8; ++u) {
            int i = base + u * 256 + tid;
            if (i < n) {
                int c = col[i], r = row[i];
                cc[u] = c; rr[u] = r;
                bc[u] = cbkt(c, M);
                br[u] = CB + rbkt(r, N);
                atomicAdd(&lcur[bc[u]], 1);
                atomicAdd(&lcur[br[u]], 1);
            } else bc[u] = -1;
        }
        __syncthreads();
        #pragma unroll
        for (int t = 0; t < 2; ++t) {
            int tt = t * 256 + tid;
            int cnt = lcur[tt];
            int gb = (tt & (CB - 1)) * CAP + (cnt ? atomicAdd(&gcursor[tt], cnt) : 0);
            lcur[tt] = gb;                // absolute base within this dir's bins
        }
        __syncthreads();
        #pragma unroll
        for (int u = 0; u < 8; ++u) {
            if (bc[u] >= 0) {
                int pc = atomicAdd(&lcur[bc[u]], 1);
                if (pc < (bc[u] + 1) * CAP) cbins[pc] = make_int2(cc[u], rr[u]);
                int pr = atomicAdd(&lcur[br[u]], 1);
                int rb = br[u] - CB;
                if (pr < (rb + 1) * CAP) rbins[pr] = make_int2(rr[u], cc[u]);
            }
        }
        return;
    }

    // ======== gemm branch: xp tile = bf16(A@Wv)  |  Wc tile = We @ Wu_bot (block NGB)
    bool wc = ((int)blockIdx.x == NGB);
    const float* Asrc = wc ? We : A0v;
    const float* Wsrc = wc ? Wu + 128 * 128 : Wv;
    int rowsE = wc ? 128 : rows;
    int w = tid >> 6, lane = tid & 63;
    int quad = lane >> 4, l15 = lane & 15;
    int r0 = wc ? 0 : blockIdx.x * 128;
    int mh = (w >> 1) * 64, nh = (w & 1) * 64;

    // self-convert weight f32 -> bf16 planes in LDS
    #pragma unroll
    for (int it = 0; it < 8; ++it) {
        int idx = it * 256 + tid;         // 0..2047
        int pg = idx >> 7, c = idx & 127;
        union { bf16x8 v; __bf16 e[8]; } u;
        #pragma unroll
        for (int j = 0; j < 8; ++j) u.e[j] = (__bf16)Wsrc[(pg * 8 + j) * 128 + c];
        *(bf16x8*)&Ws[(size_t)idx * 8] = u.v;
    }
    f32x4 acc[4][4];
    {
        f32x4 z = {0.f, 0.f, 0.f, 0.f};
        #pragma unroll
        for (int i = 0; i < 4; ++i)
            #pragma unroll
            for (int j = 0; j < 4; ++j) acc[i][j] = z;
    }
    auto stageA = [&](int t, int b) {
        int k0 = t * 32;
        #pragma unroll
        for (int h = 0; h < 2; ++h) {
            int i = h * 256 + tid;
            int q = i >> 7, r = i & 127;
            int rr2 = min(r0 + r, rowsE - 1);
            const float* Ap = Asrc + (size_t)rr2 * D + k0 + q * 8;
            float4 f0 = *(const float4*)Ap;
            float4 f1 = *(const float4*)(Ap + 4);
            union { bf16x8 v; __bf16 e[8]; } u;
            u.e[0] = (__bf16)f0.x; u.e[1] = (__bf16)f0.y; u.e[2] = (__bf16)f0.z; u.e[3] = (__bf16)f0.w;
            u.e[4] = (__bf16)f1.x; u.e[5] = (__bf16)f1.y; u.e[6] = (__bf16)f1.z; u.e[7] = (__bf16)f1.w;
            *(bf16x8*)&As[b][i * 8] = u.v;
        }
    };
    stageA(0, 0);
    for (int t = 0; t < 4; ++t) {
        __syncthreads();
        if (t + 1 < 4) stageA(t + 1, (t + 1) & 1);
        int b = t & 1;
        bf16x8 af[4], bfr[4];
        #pragma unroll
        for (int mi = 0; mi < 4; ++mi)
            af[mi] = *(const bf16x8*)&As[b][(quad * 128 + mh + mi * 16 + l15) * 8];
        #pragma unroll
        for (int ni = 0; ni < 4; ++ni)
            bfr[ni] = *(const bf16x8*)&Ws[((t * 4 + quad) * 128 + nh + ni * 16 + l15) * 8];
        #pragma unroll
        for (int mi = 0; mi < 4; ++mi)
            #pragma unroll
            for (int ni = 0; ni < 4; ++ni)
                acc[mi][ni] = __builtin_amdgcn_mfma_f32_16x16x32_bf16(af[mi], bfr[ni], acc[mi][ni], 0, 0, 0);
    }
    #pragma unroll
    for (int ni = 0; ni < 4; ++ni) {
        int colc = nh + ni * 16 + l15;
        #pragma unroll
        for (int mi = 0; mi < 4; ++mi) {
            #pragma unroll
            for (int v = 0; v < 4; ++v) {
                int r = r0 + mh + mi * 16 + quad * 4 + v;
                if (wc) {
                    // Wc[r][c] -> final-W k-index 128+r -> plane 16+(r>>3), elem r&7
                    int rl = mh + mi * 16 + quad * 4 + v;
                    wp[(size_t)(((16 + (rl >> 3)) * 128 + colc) * 8) + (rl & 7)] = (__bf16)acc[mi][ni][v];
                } else if (r < rows) {
                    xp[(size_t)r * D + colc] = (__bf16)acc[mi][ni][v];
                }
            }
        }
    }
}

// ---------------- build CSR + fused aggM: one block per bucket (512 blocks) ----------------
// dir=1 (row-keyed): build CSR in LDS, flush roff/rlist (coalesced).
// dir=0 (col-keyed): build CSR in LDS only, then gather-mean xp rows (indices from LDS
// slist) and write e_feat directly. No coff/clist globals at all.
__global__ __launch_bounds__(1024) void build_csr(
        const int2* __restrict__ cbins, const int2* __restrict__ rbins,
        const int* __restrict__ gcursor,
        int* __restrict__ roff, int* __restrict__ rlist,
        const __bf16* __restrict__ xp, __bf16* __restrict__ ef,
        int M, int N, int E_) {
    __shared__ int hist[200];
    __shared__ int cur[200];
    __shared__ int sst[200];
    __shared__ int slist[CAP];            // 16KB ordered bucket region
    __shared__ int wsum[16];
    __shared__ int sbase, scnt;
    int b = blockIdx.x, tid = threadIdx.x;
    int dir = b >> 8, bb = b & (CB - 1);
    int tot = dir ? N : M;
    int lo = (bb * tot + CB - 1) / CB;    // ceil(bb*tot/CB): first key in bucket
    int hi = ((bb + 1) * tot + CB - 1) / CB;
    int nb = hi - lo;                     // <= 196
    if (tid < 64) {                       // wave 0: per-dir prefix over 256 bucket counts
        int c0 = min(gcursor[dir * CB + 4 * tid + 0], CAP);
        int c1 = min(gcursor[dir * CB + 4 * tid + 1], CAP);
        int c2 = min(gcursor[dir * CB + 4 * tid + 2], CAP);
        int c3 = min(gcursor[dir * CB + 4 * tid + 3], CAP);
        int ts = c0 + c1 + c2 + c3, incl = ts;
        #pragma unroll
        for (int o = 1; o < 64; o <<= 1) { int t = __shfl_up(incl, o, 64); if (tid >= o) incl += t; }
        if (tid == (bb >> 2)) {
            int q = bb & 3;
            int ex = incl - ts;
            if (q > 0) ex += c0;
            if (q > 1) ex += c1;
            if (q > 2) ex += c2;
            sbase = ex;
            scnt = (q == 0) ? c0 : (q == 1) ? c1 : (q == 2) ? c2 : c3;
        }
    }
    for (int i = tid; i < nb; i += 1024) hist[i] = 0;
    __syncthreads();
    int bcnt = scnt;
    int bstart = dir ? sbase : 0;         // dir0 works in local positions only
    const int2* bins = (dir ? rbins : cbins) + (size_t)bb * CAP;
    // load pass: pairs -> registers, histogram in LDS (bcnt <= CAP = 4*1024)
    int2 pr[4];
    #pragma unroll
    for (int u = 0; u < 4; ++u) {
        int i = u * 1024 + tid;
        if (i < bcnt) { pr[u] = bins[i]; atomicAdd(&hist[pr[u].x - lo], 1); }
        else pr[u].x = -1;
    }
    __syncthreads();
    // block exclusive scan over hist[0..nb), nb <= 196
    int lane = tid & 63, wv = tid >> 6;
    int a = (tid < nb) ? hist[tid] : 0;
    int incl = a;
    #pragma unroll
    for (int o = 1; o < 64; o <<= 1) { int t = __shfl_up(incl, o, 64); if (lane >= o) incl += t; }
    if (lane == 63) wsum[wv] = incl;
    __syncthreads();
    int wb = 0;
    for (int j = 0; j < wv; ++j) wb += wsum[j];
    int ex = bstart + wb + incl - a;
    if (tid < nb) {
        if (dir) roff[lo + tid] = ex;
        sst[tid] = ex; cur[tid] = ex;
    }
    __syncthreads();
    // place pass: registers -> ordered LDS region
    #pragma unroll
    for (int u = 0; u < 4; ++u) {
        if (pr[u].x >= 0) {
            int p = atomicAdd(&cur[pr[u].x - lo], 1);
            slist[p - bstart] = pr[u].y;
        }
    }
    __syncthreads();
    if (dir) {
        // coalesced flush of row-CSR
        for (int i = tid; i < bcnt; i += 1024) rlist[bstart + i] = slist[i];
        if (bb == 0 && tid == 0) roff[N] = E_;
        return;
    }
    // ---- fused aggM: 16 waves stride over segments; wave = 4 entry-slots x 16 col-lanes
    int slot = lane >> 4, cg = lane & 15;
    for (int k = wv; k < nb; k += 16) {
        int s = sst[k], e = cur[k];       // local positions (bstart=0)
        int cnt = e - s;
        float acc8[8];
        #pragma unroll
        for (int j = 0; j < 8; ++j) acc8[j] = 0.f;
        int i = s;
        for (; i + 8 <= e; i += 8) {
            int g0 = slist[i + slot];
            int g1 = slist[i + 4 + slot];
            bf16x8 v0 = *(const bf16x8*)&xp[(size_t)g0 * D + cg * 8];
            bf16x8 v1 = *(const bf16x8*)&xp[(size_t)g1 * D + cg * 8];
            #pragma unroll
            for (int j = 0; j < 8; ++j) acc8[j] += (float)v0[j] + (float)v1[j];
        }
        for (; i < e; i += 4) {
            int ii = i + slot;
            if (ii < e) {
                int g = slist[ii];
                bf16x8 v = *(const bf16x8*)&xp[(size_t)g * D + cg * 8];
                #pragma unroll
                for (int j = 0; j < 8; ++j) acc8[j] += (float)v[j];
            }
        }
        #pragma unroll
        for (int j = 0; j < 8; ++j) {
            acc8[j] += __shfl_xor(acc8[j], 16, 64);
            acc8[j] += __shfl_xor(acc8[j], 32, 64);
        }
        if (slot == 0) {
            float inv = 1.f / (float)max(cnt, 1);
            union { bf16x8 v; __bf16 e[8]; } u;
            #pragma unroll
            for (int j = 0; j < 8; ++j) u.e[j] = (__bf16)(acc8[j] * inv);
            *(bf16x8*)&ef[(size_t)(lo + k) * D + cg * 8] = u.v;
        }
    }
}

// ---------------- segment mean via CSR: one wave = 4 entry slots x 16 lanes ----------------
__global__ __launch_bounds__(256) void agg_mean(const __bf16* __restrict__ src, const int* __restrict__ off,
                                                const int* __restrict__ list, __bf16* __restrict__ dst,
                                                int nseg) {
    int seg = blockIdx.x * 4 + (threadIdx.x >> 6);
    if (seg >= nseg) return;
    int lane = threadIdx.x & 63;
    int slot = lane >> 4, cg = lane & 15;
    int s = off[seg], e = off[seg + 1];
    int cnt = e - s;
    float acc[8];
    #pragma unroll
    for (int j = 0; j < 8; ++j) acc[j] = 0.f;

    int i = s;
    for (; i + 8 <= e; i += 8) {
        int r0 = list[i + slot];
        int r1 = list[i + 4 + slot];
        bf16x8 v0 = *(const bf16x8*)&src[(size_t)r0 * D + cg * 8];
        bf16x8 v1 = *(const bf16x8*)&src[(size_t)r1 * D + cg * 8];
        #pragma unroll
        for (int j = 0; j < 8; ++j) acc[j] += (float)v0[j] + (float)v1[j];
    }
    for (; i < e; i += 4) {
        int ii = i + slot;
        if (ii < e) {
            int r = list[ii];
            bf16x8 v = *(const bf16x8*)&src[(size_t)r * D + cg * 8];
            #pragma unroll
            for (int j = 0; j < 8; ++j) acc[j] += (float)v[j];
        }
    }
    #pragma unroll
    for (int j = 0; j < 8; ++j) {
        acc[j] += __shfl_xor(acc[j], 16, 64);
        acc[j] += __shfl_xor(acc[j], 32, 64);
    }
    if (slot == 0) {
        float inv = 1.f / (float)max(cnt, 1);
        union { bf16x8 v; __bf16 e[8]; } u;
        #pragma unroll
        for (int j = 0; j < 8; ++j) u.e[j] = (__bf16)(acc[j] * inv);
        *(bf16x8*)&dst[(size_t)seg * D + cg * 8] = u.v;
    }
}

// ---------------- MFMA bf16 GEMM: C[rows x 128] = act( concat(A0[,A1]) @ W + b ) -------------
template<int NCHUNK, bool ABF16, bool FINAL>
__global__ __launch_bounds__(256) void gemm_mfma(const void* __restrict__ A0v,
                                                 const void* __restrict__ A1v,
                                                 const __bf16* __restrict__ Wp,
                                                 const float* __restrict__ bias,
                                                 void* __restrict__ Cv, int rows) {
    __shared__ __bf16 Ws[NCHUNK * 16 * 128 * 8];   // 32KB (NCHUNK=1) / 64KB (NCHUNK=2)
    __shared__ __bf16 As[2][4 * 128 * 8];          // 2 x 8KB
    int tid = threadIdx.x;
    int w = tid >> 6, lane = tid & 63;
    int quad = lane >> 4, l15 = lane & 15;
    int r0 = blockIdx.x * 128;
    int mh = (w >> 1) * 64, nh = (w & 1) * 64;

    #pragma unroll
    for (int it = 0; it < NCHUNK * 8; ++it) {
        int idx = it * 256 + tid;
        dma16(Wp + (size_t)idx * 8, &Ws[(size_t)idx * 8]);
    }

    f32x4 acc[4][4];
    {
        f32x4 z = {0.f, 0.f, 0.f, 0.f};
        #pragma unroll
        for (int i = 0; i < 4; ++i)
            #pragma unroll
            for (int j = 0; j < 4; ++j) acc[i][j] = z;
    }

    auto stageA = [&](int t, int b) {
        int src = t >> 2;
        int k0 = (t & 3) * 32;
        #pragma unroll
        for (int h = 0; h < 2; ++h) {
            int i = h * 256 + tid;
            int q = i >> 7, r = i & 127;
            int rr = min(r0 + r, rows - 1);
            if (ABF16) {
                const __bf16* Ap = (const __bf16*)(src ? A1v : A0v) + (size_t)rr * D + k0 + q * 8;
                dma16(Ap, &As[b][i * 8]);
            } else {
                const float* Ap = (const float*)A0v + (size_t)rr * D + k0 + q * 8;
                float4 f0 = *(const float4*)Ap;
                float4 f1 = *(const float4*)(Ap + 4);
                union { bf16x8 v; __bf16 e[8]; } u;
                u.e[0] = (__bf16)f0.x; u.e[1] = (__bf16)f0.y; u.e[2] = (__bf16)f0.z; u.e[3] = (__bf16)f0.w;
                u.e[4] = (__bf16)f1.x; u.e[5] = (__bf16)f1.y; u.e[6] = (__bf16)f1.z; u.e[7] = (__bf16)f1.w;
                *(bf16x8*)&As[b][i * 8] = u.v;
            }
        }
    };

    stageA(0, 0);
    const int T = NCHUNK * 4;
    for (int t = 0; t < T; ++t) {
        __syncthreads();                          // drains DMA for chunk t (+ Ws on t=0)
        if (t + 1 < T) stageA(t + 1, (t + 1) & 1);
        int b = t & 1;
        bf16x8 af[4], bfr[4];
        #pragma unroll
        for (int mi = 0; mi < 4; ++mi)
            af[mi] = *(const bf16x8*)&As[b][(quad * 128 + mh + mi * 16 + l15) * 8];
        #pragma unroll
        for (int ni = 0; ni < 4; ++ni)
            bfr[ni] = *(const bf16x8*)&Ws[((t * 4 + quad) * 128 + nh + ni * 16 + l15) * 8];
        #pragma unroll
        for (int mi = 0; mi < 4; ++mi)
            #pragma unroll
            for (int ni = 0; ni < 4; ++ni)
                acc[mi][ni] = __builtin_amdgcn_mfma_f32_16x16x32_bf16(af[mi], bfr[ni], acc[mi][ni], 0, 0, 0);
    }

    // ---- epilogue: C/D layout col=lane&15, row=quad*4+reg
    __bf16* Cb = (__bf16*)Cv;
    float* Cf = (float*)Cv;
    #pragma unroll
    for (int ni = 0; ni < 4; ++ni) {
        int colc = nh + ni * 16 + l15;
        float bv = FINAL ? bias[colc] : 0.f;
        #pragma unroll
        for (int mi = 0; mi < 4; ++mi) {
            #pragma unroll
            for (int v = 0; v < 4; ++v) {
                int r = r0 + mh + mi * 16 + quad * 4 + v;
                if (r < rows) {
                    float val = acc[mi][ni][v];
                    if (FINAL) Cf[(size_t)r * D + colc] = fmaxf(val + bv, 0.f);
                    else       Cb[(size_t)r * D + colc] = (__bf16)val;
                }
            }
        }
    }
}

extern "C" void kernel_launch(void* const* d_in, const int* in_sizes, int n_in,
                              void* d_out, int out_size, void* d_ws, size_t ws_size,
                              hipStream_t stream) {
    const float* x  = (const float*)d_in[0];
    const int*   ei = (const int*)d_in[1];
    const float* Wv = (const float*)d_in[2];
    const float* We = (const float*)d_in[3];
    const float* Wu = (const float*)d_in[4];
    const float* bu = (const float*)d_in[5];
    float* out = (float*)d_out;

    const int N = in_sizes[0] / D;       // 50000
    const int E = in_sizes[1] / 2;       // 500000
    const int M = MSEG;                  // 10000 (static in reference)
    const int* row = ei;
    const int* col = ei + E;

    // workspace carve-out (256B aligned)
    char* p = (char*)d_ws;
    auto alloc = [&](size_t bytes) { char* q = p; p += (bytes + 255) & ~(size_t)255; return q; };
    __bf16* xp     = (__bf16*)alloc((size_t)N * D * 2);   // 12.8MB
    __bf16* e_feat = (__bf16*)alloc((size_t)M * D * 2);   // 2.56MB
    __bf16* n_agg  = (__bf16*)alloc((size_t)N * D * 2);   // 12.8MB
    __bf16* wp     = (__bf16*)alloc((size_t)32 * 128 * 8 * 2);   // 64KB [Wu_top|Wc] planes
    int* roff  = (int*)alloc((size_t)(N + 1) * 4);
    int* rlist = (int*)alloc((size_t)E * 4);
    int2* cbins = (int2*)alloc((size_t)CB * CAP * 8);     // 8MB
    int2* rbins = (int2*)alloc((size_t)CB * CAP * 8);     // 8MB
    int* gcursor = (int*)alloc(2 * CB * 4);               // 2KB counts (zeroed per launch)

    const int NGB = (N + 127) / 128;     // gemm_v blocks
    const int SB  = (E + 2047) / 2048;   // scatter blocks

    hipMemsetAsync(gcursor, 0, 2 * CB * sizeof(int), stream);
    gemmv_scatter<<<NGB + 1 + SB, 256, 0, stream>>>(x, Wv, We, Wu, wp, xp, N, NGB,
                                                    row, col, E, gcursor, cbins, rbins, M, N);
    build_csr<<<2 * CB, 1024, 0, stream>>>(cbins, rbins, gcursor, roff, rlist,
                                           xp, e_feat, M, N, E);
    agg_mean<<<(N + 3) / 4, 256, 0, stream>>>(e_feat, roff, rlist, n_agg, N);
    gemm_mfma<2, true, true><<<(N + 127) / 128, 256, 0, stream>>>(xp, n_agg, wp, bu, out, N);
}